// Round 4
// baseline (389.445 us; speedup 1.0000x reference)
//
#include <hip/hip_runtime.h>

#define NN 100000
#define CB 13          // coarse buckets
#define CSH 13         // bucket shift: bucket = col >> 13
#define CNODES 8192    // nodes per coarse bucket

// ================= CSR build v2: two-level binning =================

// ---- coarse histogram: chist[b] = #edges with col>>13 == b ----
__global__ __launch_bounds__(256) void k_hist(const int* __restrict__ coli,
                                              int* __restrict__ chist, int E) {
    __shared__ int h[CB];
    if (threadIdx.x < CB) h[threadIdx.x] = 0;
    __syncthreads();
    int stride = gridDim.x * 256;
    for (int e = blockIdx.x * 256 + threadIdx.x; e < E; e += stride)
        atomicAdd(&h[coli[e] >> CSH], 1);
    __syncthreads();
    if (threadIdx.x < CB) atomicAdd(&chist[threadIdx.x], h[threadIdx.x]);
}

// ---- scan 13 counts -> cbase/gcursor; off[NN]=E ----
__global__ void k_meta(const int* __restrict__ chist, int* __restrict__ cbase,
                       int* __restrict__ gcursor, int* __restrict__ off, int E) {
    if (threadIdx.x == 0 && blockIdx.x == 0) {
        int s = 0;
        for (int b = 0; b < CB; ++b) { cbase[b] = s; gcursor[b] = s; s += chist[b]; }
        cbase[CB] = s;
        off[NN] = E;
    }
}

// ---- binning: scatter packed (row<<13|col_local) into coarse-bucket regions ----
#define BIN_STAGE 1024
#define BIN_FLUSH 768   // flush when cnt >= this (round adds <=256, stage never overflows)

__global__ __launch_bounds__(256) void k_bin(
    const int* __restrict__ rowi, const int* __restrict__ coli,
    int* __restrict__ gcursor, unsigned int* __restrict__ cbin, int E)
{
    __shared__ unsigned int stage[CB][BIN_STAGE];
    __shared__ int lcnt[CB];
    __shared__ int fbase[CB];
    if (threadIdx.x < CB) lcnt[threadIdx.x] = 0;
    __syncthreads();
    int stride = gridDim.x * 256;
    for (int base = blockIdx.x * 256; base < E; base += stride) {
        int e = base + threadIdx.x;
        if (e < E) {
            int col = coli[e];
            int row = rowi[e];
            int b = col >> CSH;
            unsigned int val = ((unsigned int)row << CSH) | (unsigned int)(col & (CNODES - 1));
            int pos = atomicAdd(&lcnt[b], 1);
            stage[b][pos] = val;
        }
        __syncthreads();
        if (threadIdx.x < CB)
            fbase[threadIdx.x] = (lcnt[threadIdx.x] >= BIN_FLUSH)
                ? atomicAdd(&gcursor[threadIdx.x], lcnt[threadIdx.x]) : -1;
        __syncthreads();
        for (int b = 0; b < CB; ++b) {
            int fb = fbase[b];
            if (fb >= 0) {
                int cnt = lcnt[b];
                for (int i = threadIdx.x; i < cnt; i += 256) cbin[fb + i] = stage[b][i];
            }
        }
        __syncthreads();
        if (threadIdx.x < CB && fbase[threadIdx.x] >= 0) lcnt[threadIdx.x] = 0;
        __syncthreads();
    }
    // final flush
    if (threadIdx.x < CB)
        fbase[threadIdx.x] = (lcnt[threadIdx.x] > 0)
            ? atomicAdd(&gcursor[threadIdx.x], lcnt[threadIdx.x]) : -1;
    __syncthreads();
    for (int b = 0; b < CB; ++b) {
        int fb = fbase[b];
        if (fb >= 0) {
            int cnt = lcnt[b];
            for (int i = threadIdx.x; i < cnt; i += 256) cbin[fb + i] = stage[b][i];
        }
    }
}

// ---- per-coarse-bucket CSR finish: hist -> in-LDS scan -> off/dinv -> place srcs ----
__global__ __launch_bounds__(1024) void k_csr(
    const unsigned int* __restrict__ cbin, const int* __restrict__ cbase,
    int* __restrict__ off, float* __restrict__ dinv,
    int* __restrict__ srcs, int n)
{
    __shared__ int hist[CNODES];   // becomes per-node cursor after scan
    __shared__ int wsum[16];
    int b = blockIdx.x;
    int beg = cbase[b], end = cbase[b + 1];
    for (int i = threadIdx.x; i < CNODES; i += 1024) hist[i] = 0;
    __syncthreads();
    // pass A: per-node histogram
    for (int e = beg + threadIdx.x; e < end; e += 1024)
        atomicAdd(&hist[cbin[e] & (CNODES - 1)], 1);
    __syncthreads();
    // scan: thread owns hist[t*8 .. t*8+7]
    int base0 = threadIdx.x * 8;
    int v[8];
    int s = 0;
    #pragma unroll
    for (int k = 0; k < 8; ++k) { v[k] = hist[base0 + k]; s += v[k]; }
    int lane = threadIdx.x & 63;
    int wid  = threadIdx.x >> 6;
    int incl = s;
    #pragma unroll
    for (int d = 1; d < 64; d <<= 1) {
        int t = __shfl_up(incl, d, 64);
        if (lane >= d) incl += t;
    }
    if (lane == 63) wsum[wid] = incl;
    __syncthreads();
    if (wid == 0) {
        int ws = (lane < 16) ? wsum[lane] : 0;
        int wincl = ws;
        #pragma unroll
        for (int d = 1; d < 16; d <<= 1) {
            int t = __shfl_up(wincl, d, 64);
            if (lane >= d) wincl += t;
        }
        if (lane < 16) wsum[lane] = wincl - ws;   // exclusive wave base
    }
    __syncthreads();
    int excl = wsum[wid] + incl - s;   // exclusive prefix of this thread's chunk
    int nodebase = b << CSH;
    #pragma unroll
    for (int k = 0; k < 8; ++k) {
        int node = nodebase + base0 + k;
        if (node < n) {
            off[node]  = beg + excl;
            dinv[node] = rsqrtf((float)(v[k] + 1));   // +1 self-loop
        }
        hist[base0 + k] = excl;
        excl += v[k];
    }
    __syncthreads();
    // pass B: place rows
    for (int e = beg + threadIdx.x; e < end; e += 1024) {
        unsigned int pv = cbin[e];
        int cl  = (int)(pv & (CNODES - 1));
        int row = (int)(pv >> CSH);
        int p = atomicAdd(&hist[cl], 1);
        srcs[beg + p] = row;
    }
}

// ================= GEMM: Y = (X @ W) * dinv[row] =================
template<int DOUT>
__global__ __launch_bounds__(256) void k_gemm_scale(
    const float* __restrict__ X, const float* __restrict__ W,
    const float* __restrict__ dinv, float* __restrict__ Y, int n)
{
    constexpr int TPR = DOUT / 4;
    constexpr int R   = 256 / TPR;
    __shared__ float sW[64 * DOUT];
    __shared__ float sX[R * 64];

    for (int i = threadIdx.x; i < 64 * DOUT; i += 256) sW[i] = W[i];
    int r0 = blockIdx.x * R;
    for (int i = threadIdx.x; i < R * 64; i += 256) {
        int r = r0 + (i >> 6);
        sX[i] = (r < n) ? X[(size_t)r * 64 + (i & 63)] : 0.0f;
    }
    __syncthreads();

    int lr  = threadIdx.x / TPR;
    int c4  = (threadIdx.x % TPR) * 4;
    int row = r0 + lr;
    const float* xr = &sX[lr * 64];
    float4 acc = make_float4(0.f, 0.f, 0.f, 0.f);
    #pragma unroll
    for (int k = 0; k < 64; ++k) {
        float xv = xr[k];
        const float* wr = &sW[k * DOUT + c4];
        acc.x = fmaf(xv, wr[0], acc.x);
        acc.y = fmaf(xv, wr[1], acc.y);
        acc.z = fmaf(xv, wr[2], acc.z);
        acc.w = fmaf(xv, wr[3], acc.w);
    }
    if (row < n) {
        float s = dinv[row];
        acc.x *= s; acc.y *= s; acc.z *= s; acc.w *= s;
        *(float4*)&Y[(size_t)row * DOUT + c4] = acc;
    }
}

// ================= CSR aggregate: O = [relu](dinv[i]*(Y[i] + sum_in Y[src]) + b) ===========
template<bool RELU>
__global__ __launch_bounds__(256) void k_agg64(
    const float* __restrict__ Y, const int* __restrict__ off, const int* __restrict__ srcs,
    const float* __restrict__ dinv, const float* __restrict__ bias,
    float* __restrict__ O, int n)
{
    int node = blockIdx.x * 4 + (threadIdx.x >> 6);
    if (node >= n) return;
    int c = threadIdx.x & 63;
    int j = off[node], end = off[node + 1];
    float s0 = Y[(size_t)node * 64 + c];   // self-loop
    float s1 = 0.f, s2 = 0.f, s3 = 0.f;
    for (; j + 4 <= end; j += 4) {
        int a = srcs[j], b = srcs[j + 1], c2 = srcs[j + 2], d = srcs[j + 3];
        s0 += Y[(size_t)a  * 64 + c];
        s1 += Y[(size_t)b  * 64 + c];
        s2 += Y[(size_t)c2 * 64 + c];
        s3 += Y[(size_t)d  * 64 + c];
    }
    for (; j < end; ++j) s0 += Y[(size_t)srcs[j] * 64 + c];
    float s = (s0 + s1) + (s2 + s3);
    float o = fmaf(dinv[node], s, bias[c]);
    if (RELU) o = fmaxf(o, 0.f);
    O[(size_t)node * 64 + c] = o;
}

template<bool RELU>
__global__ __launch_bounds__(256) void k_agg32(
    const float* __restrict__ Y, const int* __restrict__ off, const int* __restrict__ srcs,
    const float* __restrict__ dinv, const float* __restrict__ bias,
    float* __restrict__ O, int n)
{
    int node = blockIdx.x * 8 + (threadIdx.x >> 5);
    if (node >= n) return;
    int c = threadIdx.x & 31;
    int j = off[node], end = off[node + 1];
    float s0 = Y[(size_t)node * 32 + c];   // self-loop
    float s1 = 0.f, s2 = 0.f, s3 = 0.f;
    for (; j + 4 <= end; j += 4) {
        int a = srcs[j], b = srcs[j + 1], c2 = srcs[j + 2], d = srcs[j + 3];
        s0 += Y[(size_t)a  * 32 + c];
        s1 += Y[(size_t)b  * 32 + c];
        s2 += Y[(size_t)c2 * 32 + c];
        s3 += Y[(size_t)d  * 32 + c];
    }
    for (; j < end; ++j) s0 += Y[(size_t)srcs[j] * 32 + c];
    float s = (s0 + s1) + (s2 + s3);
    float o = fmaf(dinv[node], s, bias[c]);
    if (RELU) o = fmaxf(o, 0.f);
    O[(size_t)node * 32 + c] = o;
}

extern "C" void kernel_launch(void* const* d_in, const int* in_sizes, int n_in,
                              void* d_out, int out_size, void* d_ws, size_t ws_size,
                              hipStream_t stream) {
    const float* x  = (const float*)d_in[0];
    const int*   ei = (const int*)d_in[1];
    const float* W1 = (const float*)d_in[2];
    const float* b1 = (const float*)d_in[3];
    const float* W2 = (const float*)d_in[4];
    const float* b2 = (const float*)d_in[5];
    float* out = (float*)d_out;

    const int n = NN;
    const int E = in_sizes[1] / 2;
    const int* rowi = ei;
    const int* coli = ei + E;

    // workspace layout (cbin aliases Y2: cbin dead after k_csr, Y2 written in layer 2)
    char* p = (char*)d_ws;
    int*   meta   = (int*)p;            p += 64 * 4;                 // chist[13],cbase[14],gcursor[13]
    int*   chist  = meta;
    int*   cbase  = meta + 16;
    int*   gcur   = meta + 32;
    int*   off    = (int*)p;            p += (size_t)(n + 1) * 4;
    float* dinv   = (float*)p;          p += (size_t)n * 4;
    int*   srcs   = (int*)p;            p += (size_t)E * 4;
    float* Y1     = (float*)p;          p += (size_t)n * 64 * 4;
    float* H      = (float*)p;          p += (size_t)n * 64 * 4;
    float* Y2     = (float*)p;          p += (size_t)n * 32 * 4;
    unsigned int* cbin = (unsigned int*)Y2;   // alias

    // ---- CSR build (shared across both layers) ----
    hipMemsetAsync(meta, 0, 64 * 4, stream);
    k_hist<<<256, 256, 0, stream>>>(coli, chist, E);
    k_meta<<<1, 64, 0, stream>>>(chist, cbase, gcur, off, E);
    k_bin<<<128, 256, 0, stream>>>(rowi, coli, gcur, cbin, E);
    k_csr<<<CB, 1024, 0, stream>>>(cbin, cbase, off, dinv, srcs, n);

    // ---- layer 1 (in 64 -> hid 64, relu) ----
    k_gemm_scale<64><<<(n + 15) / 16, 256, 0, stream>>>(x, W1, dinv, Y1, n);
    k_agg64<true><<<(n + 3) / 4, 256, 0, stream>>>(Y1, off, srcs, dinv, b1, H, n);

    // ---- layer 2 (hid 64 -> out 32) ----
    k_gemm_scale<32><<<(n + 31) / 32, 256, 0, stream>>>(H, W2, dinv, Y2, n);
    k_agg32<false><<<(n + 7) / 8, 256, 0, stream>>>(Y2, off, srcs, dinv, b2, out, n);
}